// Round 5
// baseline (329.198 us; speedup 1.0000x reference)
//
#include <hip/hip_runtime.h>

typedef __bf16 bf16;
typedef __attribute__((ext_vector_type(8))) __bf16 bf16x8;
typedef __attribute__((ext_vector_type(4))) __bf16 bf16x4;
typedef __attribute__((ext_vector_type(4))) float f32x4;

#define MFMA16(a, b, c) __builtin_amdgcn_mfma_f32_16x16x32_bf16((a), (b), (c), 0, 0, 0)

typedef __attribute__((address_space(1))) const void* gas_t;
typedef __attribute__((address_space(3))) void* las_t;
#define GLOAD_LDS16(g, l) \
    __builtin_amdgcn_global_load_lds((gas_t)(g), (las_t)(l), 16, 0, 0)

// ---------------------------------------------------------------------------
// fp32 -> bf16 convert (vectorized, grid-stride). n8 = elements/8.
// ---------------------------------------------------------------------------
__global__ __launch_bounds__(256) void cvt_bf16(const float* __restrict__ s,
                                                bf16* __restrict__ d, int n8) {
    for (int i = blockIdx.x * 256 + threadIdx.x; i < n8; i += gridDim.x * 256) {
        const f32x4* sp = reinterpret_cast<const f32x4*>(s + (size_t)i * 8);
        f32x4 a = sp[0], b = sp[1];
        bf16x8 h;
        h[0] = (bf16)a[0]; h[1] = (bf16)a[1]; h[2] = (bf16)a[2]; h[3] = (bf16)a[3];
        h[4] = (bf16)b[0]; h[5] = (bf16)b[1]; h[6] = (bf16)b[2]; h[7] = (bf16)b[3];
        *reinterpret_cast<bf16x8*>(d + (size_t)i * 8) = h;
    }
}

// ---------------------------------------------------------------------------
// Transpose + fp32->bf16 convert: W[K][N] (row-major) -> Wt[N][K] bf16
// ---------------------------------------------------------------------------
__global__ void transpose_cvt(const float* __restrict__ W, bf16* __restrict__ Wt,
                              int K, int N) {
    __shared__ bf16 tile[32][33];
    int tx = threadIdx.x, ty = threadIdx.y;   // 32 x 8
    int n0 = blockIdx.x * 32, k0 = blockIdx.y * 32;
#pragma unroll
    for (int j = 0; j < 4; ++j)
        tile[ty + j * 8][tx] = (bf16)W[(size_t)(k0 + ty + j * 8) * N + n0 + tx];
    __syncthreads();
#pragma unroll
    for (int j = 0; j < 4; ++j)
        Wt[(size_t)(n0 + ty + j * 8) * K + k0 + tx] = tile[tx][ty + j * 8];
}

// ---------------------------------------------------------------------------
// GEMM: C = A[M][K] * Bt[N][K]^T   (MFMA 16x16x32 bf16, f32 accum)
// m97 structure: linear LDS [128][64] per operand, global_load_lds width-16
// staging (B always; A too when bf16). XOR-swizzle (rule #21, both sides):
//   LDS(row, blk) holds source block blk ^ (row&7)  [16B blocks]
//   write side: lane l of chunk c -> dest blk l&7, source blk (l&7)^(l>>3)
//   read  side: source blk kk*4+lg lives at LDS blk ((kk*4+lg) ^ (lr&7))
//               -- FULL 3-bit XOR (round-4 bug: only low 2 bits were XORed,
//               producing col offsets up to 88 > 63 -> OOB garbage -> NaN).
// OUT_MODE: 0 = bf16 row-major; 1 = f32 row-major;
//           2 = Kt[((b*4+hkv)*2048+s)*128+d]; 3 = Vt[((b*4+hkv)*128+d)*2048+s]
// Tiles: 128x128, BK=64, 256 threads = 4 waves, each wave 64x64.
// ---------------------------------------------------------------------------
template <bool A_F32, bool DO_ROPE, int OUT_MODE>
__global__ __launch_bounds__(256) void gemm_bt(
    const void* __restrict__ Ain, const bf16* __restrict__ Bt,
    void* __restrict__ Cout, const float* __restrict__ cosb,
    const float* __restrict__ sinb, float scale, int Nn, int Kk) {
    __shared__ bf16 As[128 * 64];
    __shared__ bf16 Bs[128 * 64];
    int tid = threadIdx.x;
    int lane = tid & 63, wid = tid >> 6;
    int lr = lane & 15, lg = lane >> 4;
    int m0 = blockIdx.y * 128, n0 = blockIdx.x * 128;
    int wr = wid >> 1, wc = wid & 1;

    // staging geometry: chunk c = wid*4+i covers LDS rows c*8..c*8+7;
    // lane l -> row c*8 + l/8, dest 16B block l%8, source block pre-swizzled.
    int srow = lane >> 3;                       // 0..7
    int scol = ((lane & 7) ^ srow) << 3;        // swizzled source col (elems)
    const bf16* Bbase = Bt + (size_t)(n0 + wid * 32 + srow) * Kk + scol;
    const bf16* Abase_h =
        A_F32 ? nullptr
              : (const bf16*)Ain + (size_t)(m0 + wid * 32 + srow) * Kk + scol;

    // fragment read row bases, fixed per thread
    int fragAr = wr * 64 + lr;
    int fragBr = wc * 64 + lr;
    int swz = lr & 7;

    f32x4 acc[4][4] = {};

    const int nk = Kk >> 6;
    for (int kt = 0; kt < nk; ++kt) {
        int k0 = kt << 6;
        if constexpr (A_F32) {
            const float* A = (const float*)Ain;
#pragma unroll
            for (int i = 0; i < 8; ++i) {
                int slot = tid + i * 256;
                int row = slot >> 4, c4 = (slot & 15) << 2;
                f32x4 v = *reinterpret_cast<const f32x4*>(
                    A + (size_t)(m0 + row) * Kk + k0 + c4);
                bf16x4 h;
                h[0] = (bf16)v[0]; h[1] = (bf16)v[1];
                h[2] = (bf16)v[2]; h[3] = (bf16)v[3];
                int blk = (c4 >> 3) ^ (row & 7);
                *reinterpret_cast<bf16x4*>(
                    &As[row * 64 + (blk << 3) + (c4 & 7)]) = h;
            }
        } else {
#pragma unroll
            for (int i = 0; i < 4; ++i)
                GLOAD_LDS16(Abase_h + (size_t)(i * 8) * Kk + k0,
                            &As[(wid * 4 + i) * 512]);
        }
#pragma unroll
        for (int i = 0; i < 4; ++i)
            GLOAD_LDS16(Bbase + (size_t)(i * 8) * Kk + k0,
                        &Bs[(wid * 4 + i) * 512]);
        __syncthreads();
#pragma unroll
        for (int kk = 0; kk < 2; ++kk) {
            int colOff = ((((kk << 2) | lg) ^ swz) << 3);  // corrected 3-bit XOR
            bf16x8 af[4], bfr[4];
#pragma unroll
            for (int mi = 0; mi < 4; ++mi)
                af[mi] = *reinterpret_cast<const bf16x8*>(
                    &As[(fragAr + mi * 16) * 64 + colOff]);
#pragma unroll
            for (int ni = 0; ni < 4; ++ni)
                bfr[ni] = *reinterpret_cast<const bf16x8*>(
                    &Bs[(fragBr + ni * 16) * 64 + colOff]);
#pragma unroll
            for (int mi = 0; mi < 4; ++mi)
#pragma unroll
                for (int ni = 0; ni < 4; ++ni)
                    acc[mi][ni] = MFMA16(af[mi], bfr[ni], acc[mi][ni]);
        }
        __syncthreads();
    }

    // ---- epilogue: C/D layout col = lane&15, row = (lane>>4)*4 + r ----
    int m_base = m0 + wr * 64, n_base = n0 + wc * 64;
#pragma unroll
    for (int mi = 0; mi < 4; ++mi) {
#pragma unroll
        for (int ni = 0; ni < 4; ++ni) {
            f32x4 v = acc[mi][ni];
            int gn = n_base + ni * 16 + lr;
            if constexpr (DO_ROPE) {
                int d = gn & 127, p = d >> 1;
                bool ev = ((d & 1) == 0);
#pragma unroll
                for (int r = 0; r < 4; ++r) {
                    int gm = m_base + mi * 16 + lg * 4 + r;
                    int s = gm & 2047;
                    float cc = cosb[s * 64 + p];
                    float ss = sinb[s * 64 + p];
                    float oth = __shfl_xor(v[r], 1);
                    v[r] = (ev ? (v[r] * cc - oth * ss)
                               : (oth * ss + v[r] * cc)) * scale;
                }
            }
            if constexpr (OUT_MODE == 0) {
                bf16* C = (bf16*)Cout;
#pragma unroll
                for (int r = 0; r < 4; ++r)
                    C[(size_t)(m_base + mi * 16 + lg * 4 + r) * Nn + gn] =
                        (bf16)v[r];
            } else if constexpr (OUT_MODE == 1) {
                float* C = (float*)Cout;
#pragma unroll
                for (int r = 0; r < 4; ++r)
                    C[(size_t)(m_base + mi * 16 + lg * 4 + r) * Nn + gn] = v[r];
            } else if constexpr (OUT_MODE == 2) {
                bf16* C = (bf16*)Cout;
                int hkv = gn >> 7, d = gn & 127;
#pragma unroll
                for (int r = 0; r < 4; ++r) {
                    int gm = m_base + mi * 16 + lg * 4 + r;
                    int bb = gm >> 11, s = gm & 2047;
                    C[((size_t)(bb * 4 + hkv) * 2048 + s) * 128 + d] = (bf16)v[r];
                }
            } else {  // OUT_MODE == 3 : VT
                bf16* C = (bf16*)Cout;
                int hkv = gn >> 7, d = gn & 127;
                int gm0 = m_base + mi * 16 + lg * 4;
                int bb = gm0 >> 11, s = gm0 & 2047;
                bf16x4 h;
#pragma unroll
                for (int r = 0; r < 4; ++r) h[r] = (bf16)v[r];
                *reinterpret_cast<bf16x4*>(
                    C + ((size_t)(bb * 4 + hkv) * 128 + d) * 2048 + s) = h;
            }
        }
    }
}

// ---------------------------------------------------------------------------
// Causal flash attention, GQA. (unchanged — known-good from round 3)
// Qp:(B,S,H,hd) bf16 (pre-scaled); Kt:(B,HKV,S,hd); Vt:(B,HKV,hd,S).
// Block = 256 thr = 4 waves, wave = 16 q-rows; q-tile 64; KBLK 64.
// Grid: (H, B, S/64) with qt = last - blockIdx.z (LPT order).
// ---------------------------------------------------------------------------
__global__ __launch_bounds__(256) void attn_kernel(
    const bf16* __restrict__ Qp, const bf16* __restrict__ Kt,
    const bf16* __restrict__ Vt, bf16* __restrict__ Ao) {
    const int S = 2048, H = 16, HKV = 4, HD = 128;
    __shared__ bf16 Klds[64][136];
    __shared__ bf16 Vlds[128][72];
    __shared__ bf16 Plds[4][16][72];

    int tid = threadIdx.x, lane = tid & 63, wid = tid >> 6;
    int lr = lane & 15, lg = lane >> 4;
    int h = blockIdx.x, b = blockIdx.y;
    int qt = (int)(gridDim.z - 1) - (int)blockIdx.z;
    int hkv = h >> 2;
    int q0 = qt * 64 + wid * 16;

    const bf16* Kbase = Kt + (size_t)(b * HKV + hkv) * S * HD;
    const bf16* Vbase = Vt + (size_t)(b * HKV + hkv) * HD * S;

    bf16x8 qf[4];
    {
        const bf16* qb = Qp + ((size_t)(b * S + q0 + lr) * H + h) * HD;
#pragma unroll
        for (int ks = 0; ks < 4; ++ks)
            qf[ks] = *reinterpret_cast<const bf16x8*>(qb + ks * 32 + lg * 8);
    }

    f32x4 O[8] = {};
    float m_run[4] = {-3e38f, -3e38f, -3e38f, -3e38f};
    float l_run[4] = {0.f, 0.f, 0.f, 0.f};

    for (int kb = 0; kb <= qt; ++kb) {
        int s0 = kb * 64;
        bf16x8 kreg[4], vreg[4];
#pragma unroll
        for (int i = 0; i < 4; ++i) {
            int slot = tid + i * 256;
            int krow = slot >> 4, kc = (slot & 15) << 3;
            kreg[i] = *reinterpret_cast<const bf16x8*>(
                Kbase + (size_t)(s0 + krow) * HD + kc);
            int vrow = slot >> 3, vc = (slot & 7) << 3;
            vreg[i] = *reinterpret_cast<const bf16x8*>(
                Vbase + (size_t)vrow * S + s0 + vc);
        }
#pragma unroll
        for (int i = 0; i < 4; ++i) {
            int slot = tid + i * 256;
            int krow = slot >> 4, kc = (slot & 15) << 3;
            *reinterpret_cast<bf16x8*>(&Klds[krow][kc]) = kreg[i];
            int vrow = slot >> 3, vc = (slot & 7) << 3;
            *reinterpret_cast<bf16x8*>(&Vlds[vrow][vc]) = vreg[i];
        }
        __syncthreads();

        float p[4][4];
#pragma unroll
        for (int nt = 0; nt < 4; ++nt) {
            f32x4 sc = {};
#pragma unroll
            for (int ks = 0; ks < 4; ++ks) {
                bf16x8 kf = *reinterpret_cast<const bf16x8*>(
                    &Klds[nt * 16 + lr][ks * 32 + lg * 8]);
                sc = MFMA16(qf[ks], kf, sc);
            }
            if (kb == qt) {
                int cs = s0 + nt * 16 + lr;
#pragma unroll
                for (int r = 0; r < 4; ++r)
                    p[nt][r] = (cs <= q0 + lg * 4 + r) ? sc[r] : -1e30f;
            } else {
#pragma unroll
                for (int r = 0; r < 4; ++r) p[nt][r] = sc[r];
            }
        }
        float alpha[4];
#pragma unroll
        for (int r = 0; r < 4; ++r) {
            float mx = fmaxf(fmaxf(p[0][r], p[1][r]), fmaxf(p[2][r], p[3][r]));
#pragma unroll
            for (int off = 1; off < 16; off <<= 1)
                mx = fmaxf(mx, __shfl_xor(mx, off));
            float mnew = fmaxf(m_run[r], mx);
            float al = __expf(m_run[r] - mnew);
            alpha[r] = al;
            m_run[r] = mnew;
            float rs = 0.f;
#pragma unroll
            for (int nt = 0; nt < 4; ++nt) {
                p[nt][r] = __expf(p[nt][r] - mnew);
                rs += p[nt][r];
            }
#pragma unroll
            for (int off = 1; off < 16; off <<= 1) rs += __shfl_xor(rs, off);
            l_run[r] = l_run[r] * al + rs;
        }
#pragma unroll
        for (int nt = 0; nt < 4; ++nt)
#pragma unroll
            for (int r = 0; r < 4; ++r)
                Plds[wid][lg * 4 + r][nt * 16 + lr] = (bf16)p[nt][r];
#pragma unroll
        for (int n2 = 0; n2 < 8; ++n2)
#pragma unroll
            for (int r = 0; r < 4; ++r) O[n2][r] *= alpha[r];
        bf16x8 pa0 = *reinterpret_cast<const bf16x8*>(&Plds[wid][lr][lg * 8]);
        bf16x8 pa1 =
            *reinterpret_cast<const bf16x8*>(&Plds[wid][lr][32 + lg * 8]);
#pragma unroll
        for (int d2 = 0; d2 < 8; ++d2) {
            bf16x8 vf0 =
                *reinterpret_cast<const bf16x8*>(&Vlds[d2 * 16 + lr][lg * 8]);
            bf16x8 vf1 = *reinterpret_cast<const bf16x8*>(
                &Vlds[d2 * 16 + lr][32 + lg * 8]);
            O[d2] = MFMA16(pa0, vf0, O[d2]);
            O[d2] = MFMA16(pa1, vf1, O[d2]);
        }
        __syncthreads();
    }

#pragma unroll
    for (int r = 0; r < 4; ++r) {
        float inv = 1.0f / l_run[r];
        size_t gm = (size_t)(b * S + q0 + lg * 4 + r);
#pragma unroll
        for (int n2 = 0; n2 < 8; ++n2)
            Ao[(gm * H + h) * HD + n2 * 16 + lr] = (bf16)(O[n2][r] * inv);
    }
}

// ---------------------------------------------------------------------------
extern "C" void kernel_launch(void* const* d_in, const int* in_sizes, int n_in,
                              void* d_out, int out_size, void* d_ws,
                              size_t ws_size, hipStream_t stream) {
    const float* q = (const float*)d_in[0];
    const float* k = (const float*)d_in[1];
    const float* v = (const float*)d_in[2];
    // d_in[3] = mask (causal tril; handled analytically)
    const float* fc = (const float*)d_in[4];
    const float* fs = (const float*)d_in[5];
    const float* Wq = (const float*)d_in[6];
    const float* Wk = (const float*)d_in[7];
    const float* Wv = (const float*)d_in[8];
    const float* Wo = (const float*)d_in[9];

    char* ws = (char*)d_ws;
    bf16* Wq_t = (bf16*)(ws + 0);          //  8,388,608 B
    bf16* Wk_t = (bf16*)(ws + 8388608);    //  2,097,152
    bf16* Wv_t = (bf16*)(ws + 10485760);   //  2,097,152
    bf16* Wo_t = (bf16*)(ws + 12582912);   //  8,388,608
    bf16* Qp   = (bf16*)(ws + 20971520);   // 16,777,216
    bf16* Kt   = (bf16*)(ws + 37748736);   //  4,194,304
    bf16* Vt   = (bf16*)(ws + 41943040);   //  4,194,304
    bf16* Ao   = (bf16*)(ws + 46137344);   // 16,777,216  (end 62,914,560)
    bf16* qb   = Ao;  // q-bf16 staging; dead before attn overwrites Ao

    dim3 tb(32, 8);
    transpose_cvt<<<dim3(64, 64), tb, 0, stream>>>(Wq, Wq_t, 2048, 2048);
    transpose_cvt<<<dim3(16, 64), tb, 0, stream>>>(Wk, Wk_t, 2048, 512);
    transpose_cvt<<<dim3(16, 64), tb, 0, stream>>>(Wv, Wv_t, 2048, 512);
    transpose_cvt<<<dim3(64, 64), tb, 0, stream>>>(Wo, Wo_t, 2048, 2048);

    // q -> bf16 (8,388,608 elements)
    cvt_bf16<<<dim3(2048), 256, 0, stream>>>(q, qb, 1048576);

    const float qscale = 0.08838834764831845f;  // 1/sqrt(128)

    // Q projection + RoPE (scaled) -> Qp (B,S,H,hd)   [bf16-A fast path]
    gemm_bt<false, true, 0><<<dim3(16, 32), 256, 0, stream>>>(
        (const void*)qb, Wq_t, (void*)Qp, fc, fs, qscale, 2048, 2048);
    // K projection + RoPE -> Kt (B,HKV,S,hd)          [fp32-A path]
    gemm_bt<true, true, 2><<<dim3(4, 32), 256, 0, stream>>>(
        (const void*)k, Wk_t, (void*)Kt, fc, fs, 1.0f, 512, 2048);
    // V projection -> Vt (B,HKV,hd,S)                 [fp32-A path]
    gemm_bt<true, false, 3><<<dim3(4, 32), 256, 0, stream>>>(
        (const void*)v, Wv_t, (void*)Vt, fc, fs, 1.0f, 512, 2048);

    // attention (overwrites Ao; qb dead by now)
    attn_kernel<<<dim3(16, 2, 32), 256, 0, stream>>>(Qp, Kt, Vt, Ao);

    // Output projection -> d_out fp32                 [bf16-A fast path]
    gemm_bt<false, false, 1><<<dim3(16, 32), 256, 0, stream>>>(
        (const void*)Ao, Wo_t, d_out, fc, fs, 1.0f, 2048, 2048);
}

// Round 6
// 276.975 us; speedup vs baseline: 1.1886x; 1.1886x over previous
//
#include <hip/hip_runtime.h>

typedef __bf16 bf16;
typedef __attribute__((ext_vector_type(8))) __bf16 bf16x8;
typedef __attribute__((ext_vector_type(4))) __bf16 bf16x4;
typedef __attribute__((ext_vector_type(4))) float f32x4;

#define MFMA16(a, b, c) __builtin_amdgcn_mfma_f32_16x16x32_bf16((a), (b), (c), 0, 0, 0)

typedef __attribute__((address_space(1))) const void* gas_t;
typedef __attribute__((address_space(3))) void* las_t;
#define GLOAD_LDS16(g, l) \
    __builtin_amdgcn_global_load_lds((gas_t)(g), (las_t)(l), 16, 0, 0)

__device__ __forceinline__ unsigned pack2(float a, float b) {
    unsigned short ua = __builtin_bit_cast(unsigned short, (bf16)a);
    unsigned short ub = __builtin_bit_cast(unsigned short, (bf16)b);
    return ((unsigned)ub << 16) | (unsigned)ua;
}

// ---------------------------------------------------------------------------
// Fused transpose+cvt of all four weights: W[K][N] fp32 -> Wt[N][K] bf16.
// grid (64, 64, 4); z selects {Wq, Wo, Wk, Wv}; K = 2048 for all.
// ---------------------------------------------------------------------------
__global__ void transpose_cvt4(const float* __restrict__ Wq,
                               const float* __restrict__ Wo,
                               const float* __restrict__ Wk,
                               const float* __restrict__ Wv,
                               bf16* __restrict__ WqT, bf16* __restrict__ WoT,
                               bf16* __restrict__ WkT, bf16* __restrict__ WvT) {
    __shared__ bf16 tile[32][33];
    int z = blockIdx.z;
    const float* W = (z == 0) ? Wq : (z == 1) ? Wo : (z == 2) ? Wk : Wv;
    bf16* Wt = (z == 0) ? WqT : (z == 1) ? WoT : (z == 2) ? WkT : WvT;
    int N = (z < 2) ? 2048 : 512;
    const int K = 2048;
    int n0 = blockIdx.x * 32;
    if (n0 >= N) return;
    int k0 = blockIdx.y * 32;
    int tx = threadIdx.x, ty = threadIdx.y;  // 32 x 8
#pragma unroll
    for (int j = 0; j < 4; ++j)
        tile[ty + j * 8][tx] = (bf16)W[(size_t)(k0 + ty + j * 8) * N + n0 + tx];
    __syncthreads();
#pragma unroll
    for (int j = 0; j < 4; ++j)
        Wt[(size_t)(n0 + ty + j * 8) * K + k0 + tx] = tile[tx][ty + j * 8];
}

// ---------------------------------------------------------------------------
// GEMM: C = A[M][K] * Bt[N][K]^T   (MFMA 16x16x32 bf16, f32 accum)
// Linear LDS [128][64], global_load_lds width-16 for B (and A when bf16),
// XOR-swizzled 16B blocks on both sides (rule #21).
// OUT_MODE: 0 = bf16 row-major; 1 = f32 row-major.
// Tiles: 128x128, BK=64, 256 threads = 4 waves, each wave 64x64.
// ---------------------------------------------------------------------------
template <bool A_F32, bool DO_ROPE, int OUT_MODE>
__global__ __launch_bounds__(256) void gemm_bt(
    const void* __restrict__ Ain, const bf16* __restrict__ Bt,
    void* __restrict__ Cout, const float* __restrict__ cosb,
    const float* __restrict__ sinb, float scale, int Nn, int Kk) {
    __shared__ bf16 As[128 * 64];
    __shared__ bf16 Bs[128 * 64];
    int tid = threadIdx.x;
    int lane = tid & 63, wid = tid >> 6;
    int lr = lane & 15, lg = lane >> 4;
    int m0 = blockIdx.y * 128, n0 = blockIdx.x * 128;
    int wr = wid >> 1, wc = wid & 1;

    int srow = lane >> 3;                 // 0..7
    int scol = ((lane & 7) ^ srow) << 3;  // swizzled source col (elems)
    const bf16* Bbase = Bt + (size_t)(n0 + wid * 32 + srow) * Kk + scol;
    const bf16* Abase_h =
        A_F32 ? nullptr
              : (const bf16*)Ain + (size_t)(m0 + wid * 32 + srow) * Kk + scol;

    int fragAr = wr * 64 + lr;
    int fragBr = wc * 64 + lr;
    int swz = lr & 7;

    f32x4 acc[4][4] = {};

    const int nk = Kk >> 6;
    for (int kt = 0; kt < nk; ++kt) {
        int k0 = kt << 6;
        if constexpr (A_F32) {
            const float* A = (const float*)Ain;
#pragma unroll
            for (int i = 0; i < 8; ++i) {
                int slot = tid + i * 256;
                int row = slot >> 4, c4 = (slot & 15) << 2;
                f32x4 v = *reinterpret_cast<const f32x4*>(
                    A + (size_t)(m0 + row) * Kk + k0 + c4);
                bf16x4 h;
                h[0] = (bf16)v[0]; h[1] = (bf16)v[1];
                h[2] = (bf16)v[2]; h[3] = (bf16)v[3];
                int blk = (c4 >> 3) ^ (row & 7);
                *reinterpret_cast<bf16x4*>(
                    &As[row * 64 + (blk << 3) + (c4 & 7)]) = h;
            }
        } else {
#pragma unroll
            for (int i = 0; i < 4; ++i)
                GLOAD_LDS16(Abase_h + (size_t)(i * 8) * Kk + k0,
                            &As[(wid * 4 + i) * 512]);
        }
#pragma unroll
        for (int i = 0; i < 4; ++i)
            GLOAD_LDS16(Bbase + (size_t)(i * 8) * Kk + k0,
                        &Bs[(wid * 4 + i) * 512]);
        __syncthreads();
#pragma unroll
        for (int kk = 0; kk < 2; ++kk) {
            int colOff = ((((kk << 2) | lg) ^ swz) << 3);
            bf16x8 af[4], bfr[4];
#pragma unroll
            for (int mi = 0; mi < 4; ++mi)
                af[mi] = *reinterpret_cast<const bf16x8*>(
                    &As[(fragAr + mi * 16) * 64 + colOff]);
#pragma unroll
            for (int ni = 0; ni < 4; ++ni)
                bfr[ni] = *reinterpret_cast<const bf16x8*>(
                    &Bs[(fragBr + ni * 16) * 64 + colOff]);
#pragma unroll
            for (int mi = 0; mi < 4; ++mi)
#pragma unroll
                for (int ni = 0; ni < 4; ++ni)
                    acc[mi][ni] = MFMA16(af[mi], bfr[ni], acc[mi][ni]);
        }
        __syncthreads();
    }

    int m_base = m0 + wr * 64, n_base = n0 + wc * 64;
#pragma unroll
    for (int mi = 0; mi < 4; ++mi) {
#pragma unroll
        for (int ni = 0; ni < 4; ++ni) {
            f32x4 v = acc[mi][ni];
            int gn = n_base + ni * 16 + lr;
            if constexpr (DO_ROPE) {
                int d = gn & 127, p = d >> 1;
                bool ev = ((d & 1) == 0);
#pragma unroll
                for (int r = 0; r < 4; ++r) {
                    int gm = m_base + mi * 16 + lg * 4 + r;
                    int s = gm & 2047;
                    float cc = cosb[s * 64 + p];
                    float ss = sinb[s * 64 + p];
                    float oth = __shfl_xor(v[r], 1);
                    v[r] = (ev ? (v[r] * cc - oth * ss)
                               : (oth * ss + v[r] * cc)) * scale;
                }
            }
            if constexpr (OUT_MODE == 0) {
                bf16* C = (bf16*)Cout;
#pragma unroll
                for (int r = 0; r < 4; ++r)
                    C[(size_t)(m_base + mi * 16 + lg * 4 + r) * Nn + gn] =
                        (bf16)v[r];
            } else {
                float* C = (float*)Cout;
#pragma unroll
                for (int r = 0; r < 4; ++r)
                    C[(size_t)(m_base + mi * 16 + lg * 4 + r) * Nn + gn] = v[r];
            }
        }
    }
}

// ---------------------------------------------------------------------------
// Fused K+V projection (both fp32-A, N=512, K=2048). grid (4, 32, 2):
// z=0: K-proj + RoPE -> Kt[((b*4+hkv)*2048+s)*128+d]
// z=1: V-proj        -> Vt[((b*4+hkv)*128+d)*2048+s]
// Same GEMM body as gemm_bt fp32-A path.
// ---------------------------------------------------------------------------
__global__ __launch_bounds__(256) void gemm_kv(
    const float* __restrict__ kin, const float* __restrict__ vin,
    const bf16* __restrict__ WkT, const bf16* __restrict__ WvT,
    bf16* __restrict__ Kt, bf16* __restrict__ Vt,
    const float* __restrict__ cosb, const float* __restrict__ sinb) {
    const int Nn = 512, Kk = 2048;
    __shared__ bf16 As[128 * 64];
    __shared__ bf16 Bs[128 * 64];
    bool isK = (blockIdx.z == 0);
    const float* A = isK ? kin : vin;
    const bf16* Bt = isK ? WkT : WvT;

    int tid = threadIdx.x;
    int lane = tid & 63, wid = tid >> 6;
    int lr = lane & 15, lg = lane >> 4;
    int m0 = blockIdx.y * 128, n0 = blockIdx.x * 128;
    int wr = wid >> 1, wc = wid & 1;

    int srow = lane >> 3;
    int scol = ((lane & 7) ^ srow) << 3;
    const bf16* Bbase = Bt + (size_t)(n0 + wid * 32 + srow) * Kk + scol;

    int fragAr = wr * 64 + lr;
    int fragBr = wc * 64 + lr;
    int swz = lr & 7;

    f32x4 acc[4][4] = {};

    for (int kt = 0; kt < 32; ++kt) {
        int k0 = kt << 6;
#pragma unroll
        for (int i = 0; i < 8; ++i) {
            int slot = tid + i * 256;
            int row = slot >> 4, c4 = (slot & 15) << 2;
            f32x4 v = *reinterpret_cast<const f32x4*>(
                A + (size_t)(m0 + row) * Kk + k0 + c4);
            bf16x4 h;
            h[0] = (bf16)v[0]; h[1] = (bf16)v[1];
            h[2] = (bf16)v[2]; h[3] = (bf16)v[3];
            int blk = (c4 >> 3) ^ (row & 7);
            *reinterpret_cast<bf16x4*>(&As[row * 64 + (blk << 3) + (c4 & 7)]) = h;
        }
#pragma unroll
        for (int i = 0; i < 4; ++i)
            GLOAD_LDS16(Bbase + (size_t)(i * 8) * Kk + k0,
                        &Bs[(wid * 4 + i) * 512]);
        __syncthreads();
#pragma unroll
        for (int kk = 0; kk < 2; ++kk) {
            int colOff = ((((kk << 2) | lg) ^ swz) << 3);
            bf16x8 af[4], bfr[4];
#pragma unroll
            for (int mi = 0; mi < 4; ++mi)
                af[mi] = *reinterpret_cast<const bf16x8*>(
                    &As[(fragAr + mi * 16) * 64 + colOff]);
#pragma unroll
            for (int ni = 0; ni < 4; ++ni)
                bfr[ni] = *reinterpret_cast<const bf16x8*>(
                    &Bs[(fragBr + ni * 16) * 64 + colOff]);
#pragma unroll
            for (int mi = 0; mi < 4; ++mi)
#pragma unroll
                for (int ni = 0; ni < 4; ++ni)
                    acc[mi][ni] = MFMA16(af[mi], bfr[ni], acc[mi][ni]);
        }
        __syncthreads();
    }

    int m_base = m0 + wr * 64, n_base = n0 + wc * 64;
#pragma unroll
    for (int mi = 0; mi < 4; ++mi) {
#pragma unroll
        for (int ni = 0; ni < 4; ++ni) {
            f32x4 v = acc[mi][ni];
            int gn = n_base + ni * 16 + lr;
            int hkv = gn >> 7, d = gn & 127;
            if (isK) {
                int p = d >> 1;
                bool ev = ((d & 1) == 0);
#pragma unroll
                for (int r = 0; r < 4; ++r) {
                    int gm = m_base + mi * 16 + lg * 4 + r;
                    int s = gm & 2047;
                    float cc = cosb[s * 64 + p];
                    float ss = sinb[s * 64 + p];
                    float oth = __shfl_xor(v[r], 1);
                    float rv = ev ? (v[r] * cc - oth * ss) : (oth * ss + v[r] * cc);
                    int bb = gm >> 11;
                    Kt[((size_t)(bb * 4 + hkv) * 2048 + s) * 128 + d] = (bf16)rv;
                }
            } else {
                int gm0 = m_base + mi * 16 + lg * 4;
                int bb = gm0 >> 11, s = gm0 & 2047;
                bf16x4 hh;
#pragma unroll
                for (int r = 0; r < 4; ++r) hh[r] = (bf16)v[r];
                *reinterpret_cast<bf16x4*>(
                    Vt + ((size_t)(bb * 4 + hkv) * 128 + d) * 2048 + s) = hh;
            }
        }
    }
}

// ---------------------------------------------------------------------------
// Causal flash attention, GQA, swapped-operand (lane-local P rows).
// Qp:(B,S,H,hd) bf16 pre-scaled; Kt:(B,HKV,S,hd); Vt:(B,HKV,hd,S).
// QK^T computed as mfma(K,Q) -> S^T: lane (lr,lg) holds
//   S[s = s0 + nt*16 + lg*4 + r][q = q0+lr]  (16 scores of ONE q-row).
// Softmax: 15 in-lane fmax/add + 2 shfl_xor(16,32); m/l are per-lane scalars.
// P redistribution to PV B-fragments: pack to bf16 pairs + 16 __shfl
//   (pf_ks[jj] = P[ks*32+lg*8+jj][lr] comes from lane 2*(lg&1)+(jj>>2) | *16+lr,
//    register pk[2*ks + (lg>>1)][jj>>2 ? ... derived & verified).
// PV: mfma(V^T, P) -> O^T[d][q]; d = d2*16 + lg*4 + r, q = lr.
// Block = 256 thr = 4 waves, wave = 16 q-rows; q-tile 64; KBLK 64.
// Grid: (H, B, S/64) with qt = last - blockIdx.z (LPT order).
// ---------------------------------------------------------------------------
__global__ __launch_bounds__(256) void attn_kernel(
    const bf16* __restrict__ Qp, const bf16* __restrict__ Kt,
    const bf16* __restrict__ Vt, bf16* __restrict__ Ao) {
    const int S = 2048, H = 16, HKV = 4, HD = 128;
    __shared__ bf16 Klds[64][136];
    __shared__ bf16 Vlds[128][72];

    int tid = threadIdx.x, lane = tid & 63, wid = tid >> 6;
    int lr = lane & 15, lg = lane >> 4;
    int h = blockIdx.x, b = blockIdx.y;
    int qt = (int)(gridDim.z - 1) - (int)blockIdx.z;
    int hkv = h >> 2;
    int q0 = qt * 64 + wid * 16;
    int qrow = q0 + lr;

    const bf16* Kbase = Kt + (size_t)(b * HKV + hkv) * S * HD;
    const bf16* Vbase = Vt + (size_t)(b * HKV + hkv) * HD * S;

    // Q fragments (B-operand: col=lane&15=q, k=lg*8+j over d)
    bf16x8 qf[4];
    {
        const bf16* qb = Qp + ((size_t)(b * S + qrow) * H + h) * HD;
#pragma unroll
        for (int ks = 0; ks < 4; ++ks)
            qf[ks] = *reinterpret_cast<const bf16x8*>(qb + ks * 32 + lg * 8);
    }

    f32x4 O[8] = {};
    float m_run = -3e38f, l_run = 0.f;
    int src0 = ((lane >> 4) & 1) * 32 + lr;  // owner lane lg_o=2*(lg&1)
    int src1 = src0 + 16;                    // owner lane lg_o=2*(lg&1)+1
    bool h1 = (lg >> 1) != 0;                // selects pk row nt* = lg>>1

    for (int kb = 0; kb <= qt; ++kb) {
        int s0 = kb * 64;
        // ---- stage K (64x128) and V (128x64), vectorized (unchanged) ----
        bf16x8 kreg[4], vreg[4];
#pragma unroll
        for (int i = 0; i < 4; ++i) {
            int slot = tid + i * 256;
            int krow = slot >> 4, kc = (slot & 15) << 3;
            kreg[i] = *reinterpret_cast<const bf16x8*>(
                Kbase + (size_t)(s0 + krow) * HD + kc);
            int vrow = slot >> 3, vc = (slot & 7) << 3;
            vreg[i] = *reinterpret_cast<const bf16x8*>(
                Vbase + (size_t)vrow * S + s0 + vc);
        }
#pragma unroll
        for (int i = 0; i < 4; ++i) {
            int slot = tid + i * 256;
            int krow = slot >> 4, kc = (slot & 15) << 3;
            *reinterpret_cast<bf16x8*>(&Klds[krow][kc]) = kreg[i];
            int vrow = slot >> 3, vc = (slot & 7) << 3;
            *reinterpret_cast<bf16x8*>(&Vlds[vrow][vc]) = vreg[i];
        }
        __syncthreads();

        // ---- S^T = mfma(K, Q): lane holds 16 scores of q-row lr ----
        float p[4][4];
#pragma unroll
        for (int nt = 0; nt < 4; ++nt) {
            f32x4 sc = {};
#pragma unroll
            for (int ks = 0; ks < 4; ++ks) {
                bf16x8 kf = *reinterpret_cast<const bf16x8*>(
                    &Klds[nt * 16 + lr][ks * 32 + lg * 8]);
                sc = MFMA16(kf, qf[ks], sc);
            }
            if (kb == qt) {
                int sa = s0 + nt * 16 + lg * 4;
#pragma unroll
                for (int r = 0; r < 4; ++r)
                    p[nt][r] = (sa + r <= qrow) ? sc[r] : -1e30f;
            } else {
#pragma unroll
                for (int r = 0; r < 4; ++r) p[nt][r] = sc[r];
            }
        }
        // ---- online softmax: in-lane reduce + 2 shfl (lanes lr,lr+16,+32,+48)
        float mx = p[0][0];
#pragma unroll
        for (int nt = 0; nt < 4; ++nt)
#pragma unroll
            for (int r = 0; r < 4; ++r) mx = fmaxf(mx, p[nt][r]);
        mx = fmaxf(mx, __shfl_xor(mx, 16));
        mx = fmaxf(mx, __shfl_xor(mx, 32));
        float mnew = fmaxf(m_run, mx);
        float al = __expf(m_run - mnew);
        m_run = mnew;
        float rs = 0.f;
#pragma unroll
        for (int nt = 0; nt < 4; ++nt)
#pragma unroll
            for (int r = 0; r < 4; ++r) {
                p[nt][r] = __expf(p[nt][r] - mnew);
                rs += p[nt][r];
            }
        rs += __shfl_xor(rs, 16);
        rs += __shfl_xor(rs, 32);
        l_run = l_run * al + rs;

        // ---- pack P to bf16 pairs ----
        unsigned pk00 = pack2(p[0][0], p[0][1]), pk01 = pack2(p[0][2], p[0][3]);
        unsigned pk10 = pack2(p[1][0], p[1][1]), pk11 = pack2(p[1][2], p[1][3]);
        unsigned pk20 = pack2(p[2][0], p[2][1]), pk21 = pack2(p[2][2], p[2][3]);
        unsigned pk30 = pack2(p[3][0], p[3][1]), pk31 = pack2(p[3][2], p[3][3]);
        // ---- redistribute: 16 shfl, consumers select nt by lg>>1 ----
        unsigned e00 = __shfl(pk00, src0), e01 = __shfl(pk01, src0);
        unsigned e10 = __shfl(pk10, src0), e11 = __shfl(pk11, src0);
        unsigned e20 = __shfl(pk20, src0), e21 = __shfl(pk21, src0);
        unsigned e30 = __shfl(pk30, src0), e31 = __shfl(pk31, src0);
        unsigned o00 = __shfl(pk00, src1), o01 = __shfl(pk01, src1);
        unsigned o10 = __shfl(pk10, src1), o11 = __shfl(pk11, src1);
        unsigned o20 = __shfl(pk20, src1), o21 = __shfl(pk21, src1);
        unsigned o30 = __shfl(pk30, src1), o31 = __shfl(pk31, src1);
        union U { unsigned u[4]; bf16x8 v; } P0, P1;
        P0.u[0] = h1 ? e10 : e00;
        P0.u[1] = h1 ? e11 : e01;
        P0.u[2] = h1 ? o10 : o00;
        P0.u[3] = h1 ? o11 : o01;
        P1.u[0] = h1 ? e30 : e20;
        P1.u[1] = h1 ? e31 : e21;
        P1.u[2] = h1 ? o30 : o20;
        P1.u[3] = h1 ? o31 : o21;

        // ---- rescale O ----
#pragma unroll
        for (int d2 = 0; d2 < 8; ++d2)
#pragma unroll
            for (int r = 0; r < 4; ++r) O[d2][r] *= al;
        // ---- PV: O^T += mfma(V^T, P) ----
#pragma unroll
        for (int d2 = 0; d2 < 8; ++d2) {
            bf16x8 vf0 =
                *reinterpret_cast<const bf16x8*>(&Vlds[d2 * 16 + lr][lg * 8]);
            bf16x8 vf1 = *reinterpret_cast<const bf16x8*>(
                &Vlds[d2 * 16 + lr][32 + lg * 8]);
            O[d2] = MFMA16(vf0, P0.v, O[d2]);
            O[d2] = MFMA16(vf1, P1.v, O[d2]);
        }
        __syncthreads();
    }

    // ---- epilogue: O^T[d][q=lr] -> Ao(B,S,H,hd), bf16x4 per d2 ----
    float inv = 1.0f / l_run;
    const size_t obase = ((size_t)(b * S + qrow) * H + h) * HD;
#pragma unroll
    for (int d2 = 0; d2 < 8; ++d2) {
        bf16x4 st;
#pragma unroll
        for (int r = 0; r < 4; ++r) st[r] = (bf16)(O[d2][r] * inv);
        *reinterpret_cast<bf16x4*>(const_cast<bf16*>(Ao) + obase + d2 * 16 +
                                   lg * 4) = st;
    }
}

// ---------------------------------------------------------------------------
extern "C" void kernel_launch(void* const* d_in, const int* in_sizes, int n_in,
                              void* d_out, int out_size, void* d_ws,
                              size_t ws_size, hipStream_t stream) {
    const float* q = (const float*)d_in[0];
    const float* k = (const float*)d_in[1];
    const float* v = (const float*)d_in[2];
    // d_in[3] = mask (causal tril; handled analytically)
    const float* fc = (const float*)d_in[4];
    const float* fs = (const float*)d_in[5];
    const float* Wq = (const float*)d_in[6];
    const float* Wk = (const float*)d_in[7];
    const float* Wv = (const float*)d_in[8];
    const float* Wo = (const float*)d_in[9];

    char* ws = (char*)d_ws;
    bf16* Wq_t = (bf16*)(ws + 0);          //  8,388,608 B
    bf16* Wk_t = (bf16*)(ws + 8388608);    //  2,097,152
    bf16* Wv_t = (bf16*)(ws + 10485760);   //  2,097,152
    bf16* Wo_t = (bf16*)(ws + 12582912);   //  8,388,608
    bf16* Qp   = (bf16*)(ws + 20971520);   // 16,777,216
    bf16* Kt   = (bf16*)(ws + 37748736);   //  4,194,304
    bf16* Vt   = (bf16*)(ws + 41943040);   //  4,194,304
    bf16* Ao   = (bf16*)(ws + 46137344);   // 16,777,216  (end 62,914,560)

    // all four weight transposes in one dispatch
    transpose_cvt4<<<dim3(64, 64, 4), dim3(32, 8), 0, stream>>>(
        Wq, Wo, Wk, Wv, Wq_t, Wo_t, Wk_t, Wv_t);

    const float qscale = 0.08838834764831845f;  // 1/sqrt(128)

    // Q projection + RoPE (scaled) -> Qp (B,S,H,hd)   [fp32-A path]
    gemm_bt<true, true, 0><<<dim3(16, 32), 256, 0, stream>>>(
        (const void*)q, Wq_t, (void*)Qp, fc, fs, qscale, 2048, 2048);
    // K+V projections fused (fills the GPU: 256 blocks)
    gemm_kv<<<dim3(4, 32, 2), 256, 0, stream>>>(k, v, Wk_t, Wv_t, Kt, Vt, fc,
                                                fs);

    // attention
    attn_kernel<<<dim3(16, 2, 32), 256, 0, stream>>>(Qp, Kt, Vt, Ao);

    // Output projection -> d_out fp32                 [bf16-A gload path]
    gemm_bt<false, false, 1><<<dim3(16, 32), 256, 0, stream>>>(
        (const void*)Ao, Wo_t, d_out, fc, fs, 1.0f, 2048, 2048);
}